// Round 1
// baseline (237.359 us; speedup 1.0000x reference)
//
#include <hip/hip_runtime.h>

typedef unsigned short u16;
typedef __attribute__((ext_vector_type(8))) short short8;   // 8 bf16 = 4 VGPRs (guide §3)
typedef __attribute__((ext_vector_type(4))) float f32x4;

#define D 2048
#define EPS 1e-5f

__device__ __forceinline__ u16 f2bf(float f) {
  unsigned u = __float_as_uint(f);
  u += 0x7fffu + ((u >> 16) & 1u);   // round-to-nearest-even
  return (u16)(u >> 16);
}

__device__ __forceinline__ void async16(const void* g, void* l) {
  __builtin_amdgcn_global_load_lds(
      (const __attribute__((address_space(1))) void*)g,
      (__attribute__((address_space(3))) void*)l, 16, 0, 0);
}

// ---------------- LN over full rows of x; also pre-fill out = x ----------------
__global__ __launch_bounds__(256) void ln_rows(const float* __restrict__ x,
                                               u16* __restrict__ xn,
                                               float* __restrict__ out) {
  int row = blockIdx.x;
  int t = threadIdx.x;
  const float* xr = x + (size_t)row * D;
  float v[8];
  float s = 0.f, sq = 0.f;
#pragma unroll
  for (int i = 0; i < 8; i++) {
    float a = xr[i * 256 + t];
    v[i] = a; s += a; sq += a * a;
  }
#pragma unroll
  for (int m = 32; m >= 1; m >>= 1) { s += __shfl_xor(s, m); sq += __shfl_xor(sq, m); }
  __shared__ float ps[4], pq[4];
  int w = t >> 6, lane = t & 63;
  if (lane == 0) { ps[w] = s; pq[w] = sq; }
  __syncthreads();
  s = ps[0] + ps[1] + ps[2] + ps[3];
  sq = pq[0] + pq[1] + pq[2] + pq[3];
  float mean = s * (1.f / D);
  float var = sq * (1.f / D) - mean * mean;
  float rs = rsqrtf(var + EPS);
  float* outr = out + (size_t)row * D;
  u16* xnr = xn + (size_t)row * D;
#pragma unroll
  for (int i = 0; i < 8; i++) {
    outr[i * 256 + t] = v[i];                       // out = x (residual base)
    xnr[i * 256 + t] = f2bf((v[i] - mean) * rs);
  }
}

// ---------------- transpose + fp32->bf16 convert for the 4 weights ----------------
__global__ __launch_bounds__(256) void transpose_cvt(
    const float* __restrict__ Wq, const float* __restrict__ Wk,
    const float* __restrict__ Wv, const float* __restrict__ Wo,
    u16* __restrict__ WqT, u16* __restrict__ WkT,
    u16* __restrict__ WvT, u16* __restrict__ WoT) {
  const float* src; u16* dst;
  switch (blockIdx.z) {
    case 0: src = Wq; dst = WqT; break;
    case 1: src = Wk; dst = WkT; break;
    case 2: src = Wv; dst = WvT; break;
    default: src = Wo; dst = WoT; break;
  }
  __shared__ u16 tile[64][66];   // +2 pad: conflict-free transposed reads
  int t = threadIdx.x;
  int i0 = blockIdx.x * 64, j0 = blockIdx.y * 64;
  int rr0 = t >> 6, cc = t & 63;
#pragma unroll 4
  for (int r = 0; r < 16; r++) {
    int rr = r * 4 + rr0;
    tile[rr][cc] = f2bf(src[(size_t)(i0 + rr) * D + j0 + cc]);
  }
  __syncthreads();
#pragma unroll 4
  for (int r = 0; r < 16; r++) {
    int rr = r * 4 + rr0;
    dst[(size_t)(j0 + rr) * D + i0 + cc] = tile[cc][rr];  // dst[n][k] = src[k][n]
  }
}

// ---------------- per-head (128-wide segment) LN, fp32 -> bf16 ----------------
__global__ __launch_bounds__(64) void ln_head(const float* __restrict__ in,
                                              u16* __restrict__ outb) {
  int seg = blockIdx.x;
  int t = threadIdx.x;
  const float* p = in + (size_t)seg * 128;
  float a = p[t], b = p[t + 64];
  float s = a + b, sq = a * a + b * b;
#pragma unroll
  for (int m = 32; m >= 1; m >>= 1) { s += __shfl_xor(s, m); sq += __shfl_xor(sq, m); }
  float mean = s * (1.f / 128.f);
  float var = sq * (1.f / 128.f) - mean * mean;
  float rs = rsqrtf(var + EPS);
  u16* q = outb + (size_t)seg * 128;
  q[t] = f2bf((a - mean) * rs);
  q[t + 64] = f2bf((b - mean) * rs);
}

// ---------------- shared 128x128-tile bf16 MFMA GEMM body ----------------
// A: [M,2048] bf16 row-major. Bt: [N,2048] bf16 row-major (= B^T). Optional row-perm on Bt.
// LDS chunks XOR-swizzled (slot = chunk ^ (row&7)) -> 2-way (free) frag reads.
__device__ __forceinline__ void gemm_tile(const u16* __restrict__ A,
                                          const u16* __restrict__ Bt,
                                          bool permB, int m0, int n0,
                                          int kbeg, int kend,
                                          u16* As, u16* Bs, f32x4 acc[4][4]) {
  int tid = threadIdx.x, wid = tid >> 6, lane = tid & 63;
  int q4 = lane >> 4, m16 = lane & 15;
  int wm = wid >> 1, wn = wid & 1;
  for (int kb = kbeg; kb < kend; kb += 64) {
#pragma unroll
    for (int p = 0; p < 4; p++) {
      int idx = p * 256 + tid;         // chunk id 0..1023
      int r = idx >> 3, sl = idx & 7;
      int gc = sl ^ (r & 7);           // swizzled global chunk
      async16(A + (size_t)(m0 + r) * D + kb + gc * 8, As + (p * 256 + wid * 64) * 8);
      int rb = n0 + r;
      int gr = permB ? ((rb & 127) * 16 + (rb >> 7)) : rb;  // token permutation for Vg
      async16(Bt + (size_t)gr * D + kb + gc * 8, Bs + (p * 256 + wid * 64) * 8);
    }
    __syncthreads();
#pragma unroll
    for (int ks = 0; ks < 2; ks++) {
      short8 af[4], bf[4];
      int c = ks * 4 + q4;
#pragma unroll
      for (int i = 0; i < 4; i++) {
        int ra = wm * 64 + i * 16 + m16;
        af[i] = *(const short8*)(As + ra * 64 + (c ^ (ra & 7)) * 8);
        int rb = wn * 64 + i * 16 + m16;
        bf[i] = *(const short8*)(Bs + rb * 64 + (c ^ (rb & 7)) * 8);
      }
#pragma unroll
      for (int i = 0; i < 4; i++)
#pragma unroll
        for (int j = 0; j < 4; j++)
          acc[i][j] = __builtin_amdgcn_mfma_f32_16x16x32_bf16(af[i], bf[j], acc[i][j], 0, 0, 0);
    }
    __syncthreads();
  }
}

// ---------------- mega-GEMM: Kpre (fp32), Qpre (fp32, 256 rows), Vg (bf16, permuted V^T) ----
__global__ __launch_bounds__(256) void gemm_mega(const u16* __restrict__ xn,
                                                 const u16* __restrict__ WkT,
                                                 const u16* __restrict__ WqT,
                                                 const u16* __restrict__ WvT,
                                                 float* __restrict__ Kpre,
                                                 float* __restrict__ Qpre,
                                                 u16* __restrict__ Vg) {
  __shared__ u16 As[128 * 64];
  __shared__ u16 Bs[128 * 64];
  int bx = blockIdx.x, by = blockIdx.y;
  int sel = by >> 4, nb = by & 15;
  if (sel == 1 && bx >= 2) return;   // Q needs only 256 rows
  const u16* A = (sel == 2) ? WvT : xn;
  const u16* Bt = (sel == 0) ? WkT : (sel == 1) ? WqT : xn;
  int m0 = bx * 128, n0 = nb * 128;
  f32x4 acc[4][4];
#pragma unroll
  for (int i = 0; i < 4; i++)
#pragma unroll
    for (int j = 0; j < 4; j++)
#pragma unroll
      for (int r = 0; r < 4; r++) acc[i][j][r] = 0.f;
  gemm_tile(A, Bt, sel == 2, m0, n0, 0, D, As, Bs, acc);
  int tid = threadIdx.x, wid = tid >> 6, lane = tid & 63;
  int q4 = lane >> 4, m16 = lane & 15;
  int wm = wid >> 1, wn = wid & 1;
  if (sel == 2) {
#pragma unroll
    for (int i = 0; i < 4; i++)
#pragma unroll
      for (int j = 0; j < 4; j++)
#pragma unroll
        for (int r = 0; r < 4; r++) {
          int row = m0 + wm * 64 + i * 16 + q4 * 4 + r;   // C/D: row=(lane>>4)*4+reg
          int col = n0 + wn * 64 + j * 16 + m16;          //      col=lane&15
          Vg[(size_t)row * D + col] = f2bf(acc[i][j][r]);
        }
  } else {
    float* C = (sel == 0) ? Kpre : Qpre;
#pragma unroll
    for (int i = 0; i < 4; i++)
#pragma unroll
      for (int j = 0; j < 4; j++)
#pragma unroll
        for (int r = 0; r < 4; r++) {
          int row = m0 + wm * 64 + i * 16 + q4 * 4 + r;
          int col = n0 + wn * 64 + j * 16 + m16;
          C[(size_t)row * D + col] = acc[i][j][r];
        }
  }
}

// ---------------- attention: 256 blocks = (b,h), 2 waves each, all-MFMA ----------------
__global__ __launch_bounds__(128) void attn(const u16* __restrict__ Qb,
                                            const u16* __restrict__ Kb,
                                            const u16* __restrict__ Vg,
                                            u16* __restrict__ Ob) {
  int bh = blockIdx.x;
  int b = bh & 15, h = bh >> 4;
  int tid = threadIdx.x, w = tid >> 6, lane = tid & 63;
  int q4 = lane >> 4, m16 = lane & 15;
  __shared__ float redmx[2][16];
  __shared__ float redsm[2][16];
  __shared__ float invd[16];
  __shared__ u16 P[16][136];       // bf16 probs, padded row (272B) for 2-way reads
  const float scale = 0.08838834764831845f;   // 1/sqrt(128)

  // S = Q K^T : A-frag = Q[m=lane&15][k=quad*8+j], B-frag = K[tok(n=lane&15)][k]
  short8 af[4];
#pragma unroll
  for (int dc = 0; dc < 4; dc++)
    af[dc] = *(const short8*)(Qb + (size_t)(b * 16 + m16) * D + h * 128 + dc * 32 + q4 * 8);
  f32x4 s[4];
#pragma unroll
  for (int kt = 0; kt < 4; kt++)
#pragma unroll
    for (int r = 0; r < 4; r++) s[kt][r] = 0.f;
#pragma unroll
  for (int kt = 0; kt < 4; kt++) {
    int key = w * 64 + kt * 16 + m16;
    int tok = b + 16 * key;
#pragma unroll
    for (int dc = 0; dc < 4; dc++) {
      short8 bf = *(const short8*)(Kb + (size_t)tok * D + h * 128 + dc * 32 + q4 * 8);
      s[kt] = __builtin_amdgcn_mfma_f32_16x16x32_bf16(af[dc], bf, s[kt], 0, 0, 0);
    }
  }
  // softmax: row r = q4*4+reg lives in the 16 lanes of this quad (cols = keys)
  float mx[4];
#pragma unroll
  for (int r = 0; r < 4; r++) {
    mx[r] = fmaxf(fmaxf(s[0][r], s[1][r]), fmaxf(s[2][r], s[3][r]));
#pragma unroll
    for (int msk = 1; msk < 16; msk <<= 1) mx[r] = fmaxf(mx[r], __shfl_xor(mx[r], msk));
  }
  if (m16 == 0) {
#pragma unroll
    for (int r = 0; r < 4; r++) redmx[w][q4 * 4 + r] = mx[r];
  }
  __syncthreads();
#pragma unroll
  for (int r = 0; r < 4; r++) {
    float M = fmaxf(redmx[0][q4 * 4 + r], redmx[1][q4 * 4 + r]);
    float acc = 0.f;
#pragma unroll
    for (int kt = 0; kt < 4; kt++) {
      float e = __expf((s[kt][r] - M) * scale);
      s[kt][r] = e;
      acc += e;
    }
#pragma unroll
    for (int msk = 1; msk < 16; msk <<= 1) acc += __shfl_xor(acc, msk);
    if (m16 == 0) redsm[w][q4 * 4 + r] = acc;
  }
#pragma unroll
  for (int kt = 0; kt < 4; kt++)
#pragma unroll
    for (int r = 0; r < 4; r++)
      P[q4 * 4 + r][w * 64 + kt * 16 + m16] = f2bf(s[kt][r]);
  __syncthreads();
  if (tid < 16) invd[tid] = 1.0f / (redsm[0][tid] + redsm[1][tid]);
  __syncthreads();

  // O = P V : A-frag = P[m=qrow][k=key] from LDS; B-frag = Vg[dh][b*128+key] (contiguous)
  short8 pf[4];
#pragma unroll
  for (int kc = 0; kc < 4; kc++)
    pf[kc] = *(const short8*)(&P[m16][kc * 32 + q4 * 8]);
  f32x4 o[4];
#pragma unroll
  for (int dt = 0; dt < 4; dt++)
#pragma unroll
    for (int r = 0; r < 4; r++) o[dt][r] = 0.f;
#pragma unroll
  for (int dt = 0; dt < 4; dt++) {
    int dh = h * 128 + (w * 4 + dt) * 16 + m16;
#pragma unroll
    for (int kc = 0; kc < 4; kc++) {
      short8 vf = *(const short8*)(Vg + (size_t)dh * D + b * 128 + kc * 32 + q4 * 8);
      o[dt] = __builtin_amdgcn_mfma_f32_16x16x32_bf16(pf[kc], vf, o[dt], 0, 0, 0);
    }
  }
#pragma unroll
  for (int dt = 0; dt < 4; dt++)
#pragma unroll
    for (int r = 0; r < 4; r++) {
      int row = q4 * 4 + r;
      float val = o[dt][r] * invd[row];
      Ob[(size_t)(b * 16 + row) * D + h * 128 + (w * 4 + dt) * 16 + m16] = f2bf(val);
    }
}

// ---------------- out[0:256] += O @ Wo  (split-K=4, atomic fp32 adds) ----------------
__global__ __launch_bounds__(256) void gemm_wo(const u16* __restrict__ Ob,
                                               const u16* __restrict__ WoT,
                                               float* __restrict__ out) {
  __shared__ u16 As[128 * 64];
  __shared__ u16 Bs[128 * 64];
  int m0 = blockIdx.x * 128, n0 = blockIdx.y * 128;
  int k0 = blockIdx.z * 512;
  f32x4 acc[4][4];
#pragma unroll
  for (int i = 0; i < 4; i++)
#pragma unroll
    for (int j = 0; j < 4; j++)
#pragma unroll
      for (int r = 0; r < 4; r++) acc[i][j][r] = 0.f;
  gemm_tile(Ob, WoT, false, m0, n0, k0, k0 + 512, As, Bs, acc);
  int tid = threadIdx.x, wid = tid >> 6, lane = tid & 63;
  int q4 = lane >> 4, m16 = lane & 15;
  int wm = wid >> 1, wn = wid & 1;
#pragma unroll
  for (int i = 0; i < 4; i++)
#pragma unroll
    for (int j = 0; j < 4; j++)
#pragma unroll
      for (int r = 0; r < 4; r++) {
        int row = m0 + wm * 64 + i * 16 + q4 * 4 + r;
        int col = n0 + wn * 64 + j * 16 + m16;
        atomicAdd(&out[(size_t)row * D + col], acc[i][j][r]);
      }
}

extern "C" void kernel_launch(void* const* d_in, const int* in_sizes, int n_in,
                              void* d_out, int out_size, void* d_ws, size_t ws_size,
                              hipStream_t stream) {
  const float* x  = (const float*)d_in[0];
  const float* Wq = (const float*)d_in[1];
  const float* Wk = (const float*)d_in[2];
  const float* Wv = (const float*)d_in[3];
  const float* Wo = (const float*)d_in[4];
  float* out = (float*)d_out;
  char* w = (char*)d_ws;
  const size_t MB = 1u << 20;
  u16*   xn   = (u16*)(w);              // 8 MB  bf16 LN(x)
  u16*   WqT  = (u16*)(w + 8 * MB);     // 8 MB  Wq^T bf16
  u16*   WkT  = (u16*)(w + 16 * MB);
  u16*   WvT  = (u16*)(w + 24 * MB);
  u16*   WoT  = (u16*)(w + 32 * MB);
  float* Kpre = (float*)(w + 40 * MB);  // 16 MB xn@Wk fp32
  float* Qpre = (float*)(w + 56 * MB);  // 2 MB  xn[0:256]@Wq fp32
  u16*   Kbf  = (u16*)(w + 58 * MB);    // 8 MB  head-LN'd K bf16
  u16*   Qbf  = (u16*)(w + 66 * MB);    // 1 MB
  u16*   Vg   = (u16*)(w + 67 * MB);    // 8 MB  permuted V^T bf16
  u16*   Obf  = (u16*)(w + 75 * MB);    // 1 MB  attention output bf16

  ln_rows<<<dim3(2048), dim3(256), 0, stream>>>(x, xn, out);
  transpose_cvt<<<dim3(32, 32, 4), dim3(256), 0, stream>>>(Wq, Wk, Wv, Wo, WqT, WkT, WvT, WoT);
  gemm_mega<<<dim3(16, 48), dim3(256), 0, stream>>>(xn, WkT, WqT, WvT, Kpre, Qpre, Vg);
  ln_head<<<dim3(2048 * 16), dim3(64), 0, stream>>>(Kpre, Kbf);
  ln_head<<<dim3(256 * 16), dim3(64), 0, stream>>>(Qpre, Qbf);
  attn<<<dim3(256), dim3(128), 0, stream>>>(Qbf, Kbf, Vg, Obf);
  gemm_wo<<<dim3(2, 16, 4), dim3(256), 0, stream>>>(Obf, WoT, out);
}